// Round 9
// baseline (253.839 us; speedup 1.0000x reference)
//
#include <hip/hip_runtime.h>
#include <hip/hip_fp16.h>

// CapsNet dynamic routing, B=256, P=2048, C=10, OUT=16, IN=8, 3 iters.
// R15: MFMA uh. R14 was LDS-pipe-bound: 65 LDS inst/wave/p (40 b128 W
// broadcasts + 25 lgx exchange) ~ 630cyc x 8 waves sharing one pipe = 34us
// of the 58.8us dispatch. Per-p uh is a tiny GEMM (M=160co, N=64b, K=8) ->
// mfma_f32_16x16x32_f16 with K-padding:
//   A-frag = W[p][c][o=lane&15][0..8) -- 16B of the ORIGINAL W layout;
//   B-frag = u16[b=lane&15][p][0..8)  -- the original u row; quads 1-3 = 0
//   (A's replicated values at k>=8 multiply B's zeros -> safe for any
//   consistent k-slot convention). C/D (HW-measured m89, dtype-indep):
//   lane = uh[o=(lane>>4)*4+reg][b=lane&15].
// Wave = b-quarter (w*16 + col): softmax needs only shfl_xor 16/32 (2/c),
// NO cross-wave exchange, NO per-p barrier; each (b,c,o) has one owner ->
// tail needs no cross-wave reduce. Per wave/p: 10 ds_read_b128 + 1 u-load
// + 20 swizzles + 10 MFMA + ~150 VALU (vs 65 LDS + ~300 VALU).
// MODE0 = pure MFMA accumulation (acc as C operand, ~zero VALU).
// lg in fp16 [p][b][16] (R6/R7 precedent). uh/v packed h2 -> VGPR ~110-125;
// PPB=8/GRID=1024, LDS 21KB (2-round tail) so 4 blocks/CU can reside.
// Passes: K<0>: s1=sum_p uhat; K<1>: v1=squash(.1*s1), lg2=uhat.v1 -> global,
// s2+=softmax(lg2)*uhat; K<2>: v2=squash(s2), lg3=lg2+uhat.v2, s3+=...;
// k_out: squash(s3). s partials: regs -> sA stage (stride 164) -> coalesced
// fp32 atomicAdd.

#define Bn 256
#define Pn 2048
#define Cn 10
#define On 16
#define In 8
#define ROW 160
#define BT 64
#define PPB 8
#define TPB 256
#define GRID ((Bn / BT) * (Pn / PPB)) // 4 * 256 = 1024

typedef _Float16 f16x8 __attribute__((ext_vector_type(8)));
typedef _Float16 h2f __attribute__((ext_vector_type(2)));
typedef float f32x4 __attribute__((ext_vector_type(4)));

__device__ __forceinline__ void gl_lds16(const void* g, void* l) {
  __builtin_amdgcn_global_load_lds(
      (const __attribute__((address_space(1))) unsigned int*)g,
      (__attribute__((address_space(3))) unsigned int*)l, 16, 0, 0);
}

__device__ __forceinline__ h2f pack2(float a, float b) {
  __half2 t = __floats2half2_rn(a, b);
  return *reinterpret_cast<h2f*>(&t);
}

// ---- one-time casts (layouts unchanged) ----
__global__ __launch_bounds__(256) void k_prepw(const float* __restrict__ W,
                                               _Float16* __restrict__ Wh) {
  const size_t base = (size_t)blockIdx.x * 1280;
#pragma unroll
  for (int r = 0; r < 5; ++r) {
    const int i = threadIdx.x + 256 * r;
    Wh[base + i] = (_Float16)W[base + i];
  }
}
__global__ __launch_bounds__(256) void k_prepu(const float* __restrict__ u,
                                               _Float16* __restrict__ u16) {
  const size_t base = (size_t)blockIdx.x * ((size_t)Pn * In);
#pragma unroll 8
  for (int r = 0; r < 64; ++r) {
    const int i = threadIdx.x + 256 * r;
    u16[base + i] = (_Float16)u[base + i];
  }
}

template <int MODE>
__global__ __launch_bounds__(TPB, 2) void k_cap(const _Float16* __restrict__ u16,
                                                const _Float16* __restrict__ Wh,
                                                const float* __restrict__ sPrev,
                                                float* __restrict__ sOut,
                                                _Float16* __restrict__ lg) {
  // arena: W stage (8p x 2560B = 20480) / tail sAcc[32][164] (20992B)
  __shared__ float arena[5248];
  _Float16* wH = reinterpret_cast<_Float16*>(arena);
  const int x = blockIdx.x;
  const int bt = x >> 8;   // 4 b-tiles
  const int pt = x & 255;  // 256 p-tiles; bt-sharers spaced 256 -> same XCD
  const int tid = threadIdx.x;
  const int w = tid >> 6;
  const int lane = tid & 63;
  const int col = lane & 15;  // b within wave tile; also A's m-row = o
  const int quad = lane >> 4; // o-quad in C; k-group (only quad0 real K)
  const int b = bt * BT + w * 16 + col;
  const int p0 = pt * PPB;

  // ---- stage W (original layout, linear) via async DMA ----
  {
    const char* src = reinterpret_cast<const char*>(Wh + (size_t)p0 * 1280);
    char* dst = reinterpret_cast<char*>(wH);
#pragma unroll
    for (int r = 0; r < 5; ++r)
      gl_lds16(src + r * 4096 + tid * 16, dst + r * 4096 + tid * 16);
  }

  // ---- v packed h2 (per-thread squash of sPrev), overlaps DMA ----
  h2f vh[Cn][2];
  if (MODE >= 1) {
    const float scale = (MODE == 1) ? 0.1f : 1.0f;
    const float4* sp = reinterpret_cast<const float4*>(sPrev + (size_t)b * ROW);
#pragma unroll
    for (int c = 0; c < Cn; ++c) {
      const float4 q0 = sp[c * 4 + 0], q1 = sp[c * 4 + 1];
      const float4 q2 = sp[c * 4 + 2], q3 = sp[c * 4 + 3];
      float sq = q0.x * q0.x + q0.y * q0.y + q0.z * q0.z + q0.w * q0.w;
      sq += q1.x * q1.x + q1.y * q1.y + q1.z * q1.z + q1.w * q1.w;
      sq += q2.x * q2.x + q2.y * q2.y + q2.z * q2.z + q2.w * q2.w;
      sq += q3.x * q3.x + q3.y * q3.y + q3.z * q3.z + q3.w * q3.w;
      sq *= scale * scale;
      const float fac = scale * (sq / (1.f + sq)) / sqrtf(sq + 1e-9f);
      const float4 qq = sp[c * 4 + quad]; // L1 re-hit; avoids 12 cndmask
      vh[c][0] = pack2(fac * qq.x, fac * qq.y);
      vh[c][1] = pack2(fac * qq.z, fac * qq.w);
    }
  }

  f32x4 acc[Cn];
  const f32x4 zc = {0.f, 0.f, 0.f, 0.f};
#pragma unroll
  for (int c = 0; c < Cn; ++c) acc[c] = zc;

  const _Float16* urow = u16 + ((size_t)b * Pn + p0) * In;
  f16x8 uf = *reinterpret_cast<const f16x8*>(urow);
  const f16x8 zb = {0, 0, 0, 0, 0, 0, 0, 0};
  const bool isq0 = (quad == 0);

  __syncthreads(); // drains DMA -> wH ready

  for (int ip = 0; ip < PPB; ++ip) {
    f16x8 ufn = uf;
    if (ip + 1 < PPB) // u prefetch (named reg)
      ufn = *reinterpret_cast<const f16x8*>(urow + (ip + 1) * In);
    const f16x8 ub = isq0 ? uf : zb; // quads 1-3: K-pad zeros
    const _Float16* wp = wH + ip * 1280 + col * 8; // A-frag: W[p][c][col][.]

    if (MODE == 0) {
#pragma unroll
      for (int c = 0; c < Cn; ++c) {
        const f16x8 aW = *reinterpret_cast<const f16x8*>(wp + c * 128);
        acc[c] = __builtin_amdgcn_mfma_f32_16x16x32_f16(aW, ub, acc[c], 0, 0, 0);
      }
    } else {
      const int p = p0 + ip;
      float lgprev[Cn];
      if (MODE == 2) { // issue early; hides under MFMA block
        const h2f* lh =
            reinterpret_cast<const h2f*>(lg + ((size_t)p * Bn + b) * 16);
#pragma unroll
        for (int k = 0; k < 5; ++k) {
          const h2f t = lh[k];
          lgprev[2 * k] = (float)t[0];
          lgprev[2 * k + 1] = (float)t[1];
        }
      }
      float lf[Cn];
      h2f uhh[Cn][2];
#pragma unroll
      for (int c = 0; c < Cn; ++c) {
        const f16x8 aW = *reinterpret_cast<const f16x8*>(wp + c * 128);
        const f32x4 uh =
            __builtin_amdgcn_mfma_f32_16x16x32_f16(aW, ub, zc, 0, 0, 0);
        // partial logit over this lane's 4 o's (fma_mix vs packed v)
        float lp = uh[0] * (float)vh[c][0][0];
        lp = __builtin_fmaf(uh[1], (float)vh[c][0][1], lp);
        lp = __builtin_fmaf(uh[2], (float)vh[c][1][0], lp);
        lp = __builtin_fmaf(uh[3], (float)vh[c][1][1], lp);
        lf[c] = lp;
        uhh[c][0] = pack2(uh[0], uh[1]); // keep uh packed (20 regs not 40)
        uhh[c][1] = pack2(uh[2], uh[3]);
      }
      // reduce over the 4 o-quads: 2 shuffles per c
#pragma unroll
      for (int c = 0; c < Cn; ++c) {
        lf[c] += __shfl_xor(lf[c], 16, 64);
        lf[c] += __shfl_xor(lf[c], 32, 64);
      }
      if (MODE == 2) {
#pragma unroll
        for (int c = 0; c < Cn; ++c) lf[c] += lgprev[c];
      } else if (isq0) { // store lg2 (fp16, [p][b][16], coalesced 32B/b)
        union { h2f h; unsigned v; } c0, c1, c2, c3, c4;
        c0.h = pack2(lf[0], lf[1]);
        c1.h = pack2(lf[2], lf[3]);
        c2.h = pack2(lf[4], lf[5]);
        c3.h = pack2(lf[6], lf[7]);
        c4.h = pack2(lf[8], lf[9]);
        _Float16* lrow = lg + ((size_t)p * Bn + b) * 16;
        uint4 v4 = {c0.v, c1.v, c2.v, c3.v};
        *reinterpret_cast<uint4*>(lrow) = v4;
        *reinterpret_cast<unsigned*>(lrow + 8) = c4.v;
      }
      // softmax over 10 in-lane
      float m = lf[0];
#pragma unroll
      for (int c = 1; c < Cn; ++c) m = fmaxf(m, lf[c]);
      float ss = 0.f;
#pragma unroll
      for (int c = 0; c < Cn; ++c) {
        lf[c] = __expf(lf[c] - m);
        ss += lf[c];
      }
      const float inv = 1.f / ss;
#pragma unroll
      for (int c = 0; c < Cn; ++c) {
        const float cv = lf[c] * inv;
        acc[c][0] = __builtin_fmaf(cv, (float)uhh[c][0][0], acc[c][0]);
        acc[c][1] = __builtin_fmaf(cv, (float)uhh[c][0][1], acc[c][1]);
        acc[c][2] = __builtin_fmaf(cv, (float)uhh[c][1][0], acc[c][2]);
        acc[c][3] = __builtin_fmaf(cv, (float)uhh[c][1][1], acc[c][3]);
      }
    }
    uf = ufn;
  }

  // ---- tail: each (b,c,o) has ONE owner; 2 rounds of 32 b through sA ----
  __syncthreads(); // all wH reads done before arena reuse
  float* sA = arena;
#pragma unroll
  for (int rnd = 0; rnd < 2; ++rnd) {
    if ((w >> 1) == rnd) {
      const int rrow = (w & 1) * 16 + col;
      float* dst = &sA[rrow * 164 + quad * 4]; // stride 164 -> ~2-way banks
#pragma unroll
      for (int c = 0; c < Cn; ++c)
        *reinterpret_cast<f32x4*>(dst + c * 16) = acc[c];
    }
    __syncthreads();
#pragma unroll
    for (int r = 0; r < 20; ++r) {
      const int gi = tid + 256 * r; // 5120 cells, consecutive addresses
      const int bl = gi / 160, rem = gi - 160 * bl;
      atomicAdd(&sOut[(size_t)(bt * BT + rnd * 32 + bl) * ROW + rem],
                sA[bl * 164 + rem]);
    }
    if (rnd == 0) __syncthreads(); // reads done before round-1 overwrites
  }
}

__global__ __launch_bounds__(256) void k_out(const float* __restrict__ s,
                                             float* __restrict__ out) {
  const int gi = blockIdx.x * 256 + threadIdx.x; // [0, 2560) = (b,c)
  const int b = gi / 10, c = gi - 10 * b;
  const float* sp = s + (size_t)b * ROW + c * 16;
  float sq = 0.f;
#pragma unroll
  for (int o = 0; o < On; ++o) { const float xx = sp[o]; sq += xx * xx; }
  const float fac = (sq / (1.f + sq)) / sqrtf(sq + 1e-9f);
  float* op = out + (size_t)b * ROW + c * 16;
#pragma unroll
  for (int o = 0; o < On; ++o) op[o] = fac * sp[o];
}

extern "C" void kernel_launch(void* const* d_in, const int* in_sizes, int n_in,
                              void* d_out, int out_size, void* d_ws, size_t ws_size,
                              hipStream_t stream) {
  (void)in_sizes; (void)n_in; (void)out_size;
  const float* u = (const float*)d_in[0];
  const float* W = (const float*)d_in[1];
  float* out = (float*)d_out;
  float* s1 = (float*)d_ws;                       // 3 x [256][160] fp32
  float* s2 = s1 + (size_t)Bn * ROW;
  float* s3 = s2 + (size_t)Bn * ROW;
  _Float16* lg = (_Float16*)(s3 + (size_t)Bn * ROW); // [2048][256][16] fp16, 16.8MB
  _Float16* Wh = lg + (size_t)Pn * Bn * 16;          // 5.25MB
  _Float16* uh16 = Wh + (size_t)Pn * Cn * On * In;   // 8.4MB
  const size_t need = (size_t)3 * Bn * ROW * sizeof(float) +
                      ((size_t)Pn * Bn * 16 + (size_t)Pn * Cn * On * In +
                       (size_t)Bn * Pn * In) * sizeof(_Float16);
  if (ws_size < need) return;
  hipMemsetAsync(d_ws, 0, (size_t)3 * Bn * ROW * sizeof(float), stream);
  k_prepw<<<Pn, 256, 0, stream>>>(W, Wh);
  k_prepu<<<Bn, 256, 0, stream>>>(u, uh16);
  k_cap<0><<<GRID, TPB, 0, stream>>>(uh16, Wh, s1, s1, lg);
  k_cap<1><<<GRID, TPB, 0, stream>>>(uh16, Wh, s1, s2, lg);
  k_cap<2><<<GRID, TPB, 0, stream>>>(uh16, Wh, s2, s3, lg);
  k_out<<<10, 256, 0, stream>>>(s3, out);
}

// Round 10
// 204.613 us; speedup vs baseline: 1.2406x; 1.2406x over previous
//
#include <hip/hip_runtime.h>
#include <hip/hip_fp16.h>

// CapsNet dynamic routing, B=256, P=2048, C=10, OUT=16, IN=8, 3 iters.
// R16: R15's MFMA core, skeleton deleted. Evidence (R11/R15): MODE0 ~= MODE1
// ~= MODE2 -> cost is the shared skeleton, not softmax math. Three cuts:
//  (1) NO atomics: thread owns (b,c,quad) once -> coalesced float4 partial
//      stores part[x][b_l][160] (full 64B lines); k_red (160 blocks, 21MB
//      coalesced) sums 128 p-tiles -> s. No memset, no LDS tail, no tail
//      barriers, deterministic.
//  (2) lg DELETED by algebra: b3 = uhat.v1 + uhat.v2 = uhat.(v1+v2), so
//      MODE2 reads s1,s2 and dots against packed (v1+v2). -39MB traffic,
//      less fp16 rounding.
//  (3) u transposed+cast once to uT[p][b][8] fp16 -> wave u-load = 256B
//      contiguous (4 lines, was 64 at 32KB lane stride).
// PPB=16/GRID=512 (halves R15's block count / partial volume).
// MFMA mapping (R15, verified): A = W[p][c][o=col][0..8) (original layout,
// 16B/lane), B = uT row (quad0; quads1-3 zero = K-pad), C/D lane(quad,col) =
// uh[o=quad*4+reg][b=col]. Softmax: 2 shfl_xor per c (quad reduce), all-10
// in-lane. One __syncthreads per kernel (W DMA drain).
// Passes: cap<0>: part=sum_p uhat -> red -> s1; cap<1>: v1=squash(.1 s1),
// part=sum softmax(uhat.v1)*uhat -> red -> s2; cap<2>: v12=v1+squash(s2),
// part=sum softmax(uhat.v12)*uhat -> red -> s3; k_out: squash(s3).

#define Bn 256
#define Pn 2048
#define Cn 10
#define On 16
#define In 8
#define ROW 160
#define BT 64
#define PPB 16
#define NPT (Pn / PPB)         // 128
#define TPB 256
#define GRID ((Bn / BT) * NPT) // 512

typedef _Float16 f16x8 __attribute__((ext_vector_type(8)));
typedef _Float16 h2f __attribute__((ext_vector_type(2)));
typedef float f32x4 __attribute__((ext_vector_type(4)));

__device__ __forceinline__ void gl_lds16(const void* g, void* l) {
  __builtin_amdgcn_global_load_lds(
      (const __attribute__((address_space(1))) unsigned int*)g,
      (__attribute__((address_space(3))) unsigned int*)l, 16, 0, 0);
}

__device__ __forceinline__ h2f pack2(float a, float b) {
  __half2 t = __floats2half2_rn(a, b);
  return *reinterpret_cast<h2f*>(&t);
}

// ---- one-time W cast (layout unchanged) ----
__global__ __launch_bounds__(256) void k_prepw(const float* __restrict__ W,
                                               _Float16* __restrict__ Wh) {
  const size_t base = (size_t)blockIdx.x * 1280;
#pragma unroll
  for (int r = 0; r < 5; ++r) {
    const int i = threadIdx.x + 256 * r;
    Wh[base + i] = (_Float16)W[base + i];
  }
}

// ---- one-time u transpose+cast: uT[p][b][i] (writes coalesced 4KB/block) ----
__global__ __launch_bounds__(256) void k_prepu(const float* __restrict__ u,
                                               _Float16* __restrict__ uT) {
  const int p = blockIdx.x;
  const int b = threadIdx.x;
  const float4* src = reinterpret_cast<const float4*>(u + ((size_t)b * Pn + p) * In);
  const float4 a = src[0], c = src[1];
  f16x8 o;
  o[0] = (_Float16)a.x; o[1] = (_Float16)a.y; o[2] = (_Float16)a.z; o[3] = (_Float16)a.w;
  o[4] = (_Float16)c.x; o[5] = (_Float16)c.y; o[6] = (_Float16)c.z; o[7] = (_Float16)c.w;
  *reinterpret_cast<f16x8*>(uT + ((size_t)p * Bn + b) * In) = o;
}

template <int MODE>
__global__ __launch_bounds__(TPB, 2) void k_cap(const _Float16* __restrict__ uT,
                                                const _Float16* __restrict__ Wh,
                                                const float* __restrict__ s1,
                                                const float* __restrict__ s2,
                                                float* __restrict__ part) {
  __shared__ _Float16 wH[PPB * 1280]; // 40960 B, staged once
  const int x = blockIdx.x;
  const int bt = x >> 7;   // 4 b-tiles
  const int pt = x & 127;  // 128 p-tiles
  const int tid = threadIdx.x;
  const int w = tid >> 6;
  const int lane = tid & 63;
  const int col = lane & 15;  // b within wave tile; also A's o-row
  const int quad = lane >> 4; // o-quad in C/D; k-group (only quad0 real)
  const int b = bt * BT + w * 16 + col;
  const int p0 = pt * PPB;

  // ---- stage W (original layout, linear) via async DMA: 10 x 16B rounds
  {
    const char* src = reinterpret_cast<const char*>(Wh + (size_t)p0 * 1280);
    char* dst = reinterpret_cast<char*>(wH);
#pragma unroll
    for (int r = 0; r < 10; ++r)
      gl_lds16(src + r * 4096 + tid * 16, dst + r * 4096 + tid * 16);
  }

  // ---- v packed h2 (MODE1: v1; MODE2: v1+v2), overlaps DMA ----
  h2f vh[Cn][2];
  if (MODE >= 1) {
    const float4* spA = reinterpret_cast<const float4*>(s1 + (size_t)b * ROW);
    const float4* spB = reinterpret_cast<const float4*>(s2 + (size_t)b * ROW);
#pragma unroll
    for (int c = 0; c < Cn; ++c) {
      const float4 a0 = spA[c * 4 + 0], a1 = spA[c * 4 + 1];
      const float4 a2 = spA[c * 4 + 2], a3 = spA[c * 4 + 3];
      float sqA = a0.x * a0.x + a0.y * a0.y + a0.z * a0.z + a0.w * a0.w;
      sqA += a1.x * a1.x + a1.y * a1.y + a1.z * a1.z + a1.w * a1.w;
      sqA += a2.x * a2.x + a2.y * a2.y + a2.z * a2.z + a2.w * a2.w;
      sqA += a3.x * a3.x + a3.y * a3.y + a3.z * a3.z + a3.w * a3.w;
      sqA *= 0.01f; // v1 scale is always 0.1
      const float facA = 0.1f * (sqA / (1.f + sqA)) / sqrtf(sqA + 1e-9f);
      const float4 qa = spA[c * 4 + quad]; // L1 re-hit
      float v0 = facA * qa.x, v1_ = facA * qa.y;
      float v2_ = facA * qa.z, v3_ = facA * qa.w;
      if (MODE == 2) { // add v2 = squash(s2)
        const float4 b0 = spB[c * 4 + 0], b1 = spB[c * 4 + 1];
        const float4 b2 = spB[c * 4 + 2], b3 = spB[c * 4 + 3];
        float sqB = b0.x * b0.x + b0.y * b0.y + b0.z * b0.z + b0.w * b0.w;
        sqB += b1.x * b1.x + b1.y * b1.y + b1.z * b1.z + b1.w * b1.w;
        sqB += b2.x * b2.x + b2.y * b2.y + b2.z * b2.z + b2.w * b2.w;
        sqB += b3.x * b3.x + b3.y * b3.y + b3.z * b3.z + b3.w * b3.w;
        const float facB = (sqB / (1.f + sqB)) / sqrtf(sqB + 1e-9f);
        const float4 qb = spB[c * 4 + quad];
        v0 += facB * qb.x; v1_ += facB * qb.y;
        v2_ += facB * qb.z; v3_ += facB * qb.w;
      }
      vh[c][0] = pack2(v0, v1_);
      vh[c][1] = pack2(v2_, v3_);
    }
  }

  f32x4 acc[Cn];
  const f32x4 zc = {0.f, 0.f, 0.f, 0.f};
#pragma unroll
  for (int c = 0; c < Cn; ++c) acc[c] = zc;

  const _Float16* urow = uT + ((size_t)p0 * Bn + b) * In; // coalesced per p
  f16x8 uf = *reinterpret_cast<const f16x8*>(urow);
  const f16x8 zb = {0, 0, 0, 0, 0, 0, 0, 0};
  const bool isq0 = (quad == 0);

  __syncthreads(); // drains DMA -> wH ready (the ONLY barrier)

  for (int ip = 0; ip < PPB; ++ip) {
    f16x8 ufn = uf;
    if (ip + 1 < PPB) // u prefetch (named reg); 256B/wave contiguous
      ufn = *reinterpret_cast<const f16x8*>(urow + (size_t)(ip + 1) * Bn * In);
    const f16x8 ub = isq0 ? uf : zb; // quads 1-3: K-pad zeros
    const _Float16* wp = wH + ip * 1280 + col * 8; // A: W[p][c][col][.]

    if (MODE == 0) {
#pragma unroll
      for (int c = 0; c < Cn; ++c) {
        const f16x8 aW = *reinterpret_cast<const f16x8*>(wp + c * 128);
        acc[c] = __builtin_amdgcn_mfma_f32_16x16x32_f16(aW, ub, acc[c], 0, 0, 0);
      }
    } else {
      float lf[Cn];
      h2f uhh[Cn][2];
#pragma unroll
      for (int c = 0; c < Cn; ++c) {
        const f16x8 aW = *reinterpret_cast<const f16x8*>(wp + c * 128);
        const f32x4 uh =
            __builtin_amdgcn_mfma_f32_16x16x32_f16(aW, ub, zc, 0, 0, 0);
        float lp = uh[0] * (float)vh[c][0][0];
        lp = __builtin_fmaf(uh[1], (float)vh[c][0][1], lp);
        lp = __builtin_fmaf(uh[2], (float)vh[c][1][0], lp);
        lp = __builtin_fmaf(uh[3], (float)vh[c][1][1], lp);
        lf[c] = lp;
        uhh[c][0] = pack2(uh[0], uh[1]); // packed: 20 regs not 40
        uhh[c][1] = pack2(uh[2], uh[3]);
      }
      // reduce over 4 o-quads: 2 shuffles per c (b stays in-lane)
#pragma unroll
      for (int c = 0; c < Cn; ++c) {
        lf[c] += __shfl_xor(lf[c], 16, 64);
        lf[c] += __shfl_xor(lf[c], 32, 64);
      }
      // softmax over 10 in-lane
      float m = lf[0];
#pragma unroll
      for (int c = 1; c < Cn; ++c) m = fmaxf(m, lf[c]);
      float ss = 0.f;
#pragma unroll
      for (int c = 0; c < Cn; ++c) {
        lf[c] = __expf(lf[c] - m);
        ss += lf[c];
      }
      const float inv = 1.f / ss;
#pragma unroll
      for (int c = 0; c < Cn; ++c) {
        const float cv = lf[c] * inv;
        acc[c][0] = __builtin_fmaf(cv, (float)uhh[c][0][0], acc[c][0]);
        acc[c][1] = __builtin_fmaf(cv, (float)uhh[c][0][1], acc[c][1]);
        acc[c][2] = __builtin_fmaf(cv, (float)uhh[c][1][0], acc[c][2]);
        acc[c][3] = __builtin_fmaf(cv, (float)uhh[c][1][1], acc[c][3]);
      }
    }
    uf = ufn;
  }

  // ---- partial store: owner-unique, full-line coalesced, NO atomics ----
  float* pb = part + ((size_t)x * BT + w * 16 + col) * ROW;
#pragma unroll
  for (int c = 0; c < Cn; ++c)
    *reinterpret_cast<f32x4*>(pb + c * 16 + quad * 4) = acc[c];
}

// ---- sum 128 p-tile partials -> s[b][160]; coalesced 1KB/wave per pt ----
__global__ __launch_bounds__(256) void k_red(const float* __restrict__ part,
                                             float* __restrict__ s) {
  const int cell = blockIdx.x * 256 + threadIdx.x; // [0, 40960)
  const int b = cell / 160, rem = cell - 160 * b;
  const int bt = b >> 6, bl = b & 63;
  const float* p0 = part + ((size_t)(bt * NPT) * BT + bl) * ROW + rem;
  float a0 = 0.f, a1 = 0.f, a2 = 0.f, a3 = 0.f;
  float a4 = 0.f, a5 = 0.f, a6 = 0.f, a7 = 0.f;
#pragma unroll 4
  for (int pt = 0; pt < NPT; pt += 8) { // 8 independent load chains
    a0 += p0[(size_t)(pt + 0) * BT * ROW];
    a1 += p0[(size_t)(pt + 1) * BT * ROW];
    a2 += p0[(size_t)(pt + 2) * BT * ROW];
    a3 += p0[(size_t)(pt + 3) * BT * ROW];
    a4 += p0[(size_t)(pt + 4) * BT * ROW];
    a5 += p0[(size_t)(pt + 5) * BT * ROW];
    a6 += p0[(size_t)(pt + 6) * BT * ROW];
    a7 += p0[(size_t)(pt + 7) * BT * ROW];
  }
  s[cell] = ((a0 + a1) + (a2 + a3)) + ((a4 + a5) + (a6 + a7));
}

__global__ __launch_bounds__(256) void k_out(const float* __restrict__ s,
                                             float* __restrict__ out) {
  const int gi = blockIdx.x * 256 + threadIdx.x; // [0, 2560) = (b,c)
  const int b = gi / 10, c = gi - 10 * b;
  const float* sp = s + (size_t)b * ROW + c * 16;
  float sq = 0.f;
#pragma unroll
  for (int o = 0; o < On; ++o) { const float xx = sp[o]; sq += xx * xx; }
  const float fac = (sq / (1.f + sq)) / sqrtf(sq + 1e-9f);
  float* op = out + (size_t)b * ROW + c * 16;
#pragma unroll
  for (int o = 0; o < On; ++o) op[o] = fac * sp[o];
}

extern "C" void kernel_launch(void* const* d_in, const int* in_sizes, int n_in,
                              void* d_out, int out_size, void* d_ws, size_t ws_size,
                              hipStream_t stream) {
  (void)in_sizes; (void)n_in; (void)out_size;
  const float* u = (const float*)d_in[0];
  const float* W = (const float*)d_in[1];
  float* out = (float*)d_out;
  float* s1 = (float*)d_ws;                    // 3 x [256][160] fp32
  float* s2 = s1 + (size_t)Bn * ROW;
  float* s3 = s2 + (size_t)Bn * ROW;
  float* part = s3 + (size_t)Bn * ROW;         // [512][64][160] fp32, 21MB
  _Float16* Wh = (_Float16*)(part + (size_t)GRID * BT * ROW); // 5.25MB
  _Float16* uTp = Wh + (size_t)Pn * Cn * On * In;             // 8.4MB
  const size_t need =
      ((size_t)3 * Bn * ROW + (size_t)GRID * BT * ROW) * sizeof(float) +
      ((size_t)Pn * Cn * On * In + (size_t)Pn * Bn * In) * sizeof(_Float16);
  if (ws_size < need) return;
  k_prepw<<<Pn, 256, 0, stream>>>(W, Wh);
  k_prepu<<<Pn, 256, 0, stream>>>(u, uTp);
  k_cap<0><<<GRID, TPB, 0, stream>>>(uTp, Wh, s1, s1, part);
  k_red<<<160, 256, 0, stream>>>(part, s1);
  k_cap<1><<<GRID, TPB, 0, stream>>>(uTp, Wh, s1, s1, part);
  k_red<<<160, 256, 0, stream>>>(part, s2);
  k_cap<2><<<GRID, TPB, 0, stream>>>(uTp, Wh, s1, s2, part);
  k_red<<<160, 256, 0, stream>>>(part, s3);
  k_out<<<10, 256, 0, stream>>>(s3, out);
}